// Round 9
// baseline (233.673 us; speedup 1.0000x reference)
//
#include <hip/hip_runtime.h>
#include <hip/hip_fp16.h>
#include <stdint.h>

#define BATCH 256
#define PSEL  128
#define IN_DIM 3200
#define O1_DIM 8192
#define O3_DIM 4096

typedef unsigned int u32x4 __attribute__((ext_vector_type(4)));

static __device__ inline uint32_t pack_half2(float a, float b) {
    __half2 h = __floats2half2_rn(a, b);
    return *reinterpret_cast<uint32_t*>(&h);
}

// ---------------------------------------------------------------------------
// transpose x [256, 3200] fp32 -> xT [3200, 256] fp16; zero stats.
// ---------------------------------------------------------------------------
__global__ __launch_bounds__(256) void transpose_kernel(const float* __restrict__ x,
                                                        __half* __restrict__ xT,
                                                        float* __restrict__ stats) {
    int tx = threadIdx.x;       // 32
    int ty = threadIdx.y;       // 8
    int tid = ty * 32 + tx;
    int gid = blockIdx.y * gridDim.x + blockIdx.x;
    if (gid < 4) stats[gid * 256 + tid] = 0.0f;

    __shared__ float tile[32][33];
    int i0 = blockIdx.x * 32;
    int b0 = blockIdx.y * 32;
#pragma unroll
    for (int k = 0; k < 4; ++k)
        tile[ty + k * 8][tx] =
            __builtin_nontemporal_load(&x[(size_t)(b0 + ty + k * 8) * IN_DIM + i0 + tx]);
    __syncthreads();
#pragma unroll
    for (int k = 0; k < 4; ++k)
        xT[(size_t)(i0 + ty + k * 8) * BATCH + b0 + tx] =
            __float2half(tile[tx][ty + k * 8]);
}

// ---------------------------------------------------------------------------
// precompute (layers 2/3): pack[o][p] = {sel*16 (LDS byte off), A=sig(w)*g[sel]}
// meta[o] = {sumA, sumC - bias} where C = sig(w)*be[sel].
// Block = 16 outputs; 2 outputs in flight (t>>7), 128 entries each.
// ---------------------------------------------------------------------------
__global__ __launch_bounds__(256) void pack_kernel(
    const int* __restrict__ sel, const float* __restrict__ w,
    const float* __restrict__ g, const float* __restrict__ be,
    const float* __restrict__ bias,
    uint2* __restrict__ pack, float2* __restrict__ meta) {
    const int t = threadIdx.x;
    const int slot = t >> 7;      // 0..1
    const int e = t & 127;
    const int o0 = blockIdx.x * 16;
    __shared__ float s_p[4][2];
    for (int k = 0; k < 8; ++k) {
        int o = o0 + 2 * k + slot;
        int idx  = sel[(size_t)o * PSEL + e];
        float wv = w[(size_t)o * PSEL + e];
        float sw = 1.0f / (1.0f + __expf(-wv));
        float A = sw * g[idx];
        float C = sw * be[idx];
        pack[(size_t)o * PSEL + e] = make_uint2((uint32_t)idx << 4, __float_as_uint(A));
        float va = A, vc = C;
#pragma unroll
        for (int off = 32; off > 0; off >>= 1) {
            va += __shfl_down(va, off, 64);
            vc += __shfl_down(vc, off, 64);
        }
        if ((t & 63) == 0) { s_p[t >> 6][0] = va; s_p[t >> 6][1] = vc; }
        __syncthreads();
        if (t < 2) {
            float sA = s_p[2 * t][0] + s_p[2 * t + 1][0];
            float sC = s_p[2 * t][1] + s_p[2 * t + 1][1];
            int oo = o0 + 2 * k + t;
            meta[oo] = make_float2(sA, sC - bias[oo]);
        }
        __syncthreads();
    }
}

// ---------------------------------------------------------------------------
// stats1: column sums/sumsq of h1T [8192][256] (row-major) AND emit the
// batch-blocked copy h1blk [32 slabs][8192 rows][8 cols] fp16 for LDS staging.
// 32 blocks x 256 rows; atomics 32 updates/addr.
// ---------------------------------------------------------------------------
__global__ __launch_bounds__(256) void stats_kernel(const __half* __restrict__ hT,
                                                    __half* __restrict__ hblk,
                                                    float* __restrict__ gsum,
                                                    float* __restrict__ gsq) {
    int t   = threadIdx.x;
    int col = t & 127;          // dword column (batch 2col, 2col+1)
    int rp  = t >> 7;           // row half
    int r0  = blockIdx.x * 256 + rp * 128;
    const uint32_t* p = (const uint32_t*)hT + (size_t)r0 * 128 + col;
    char* blkbase = (char*)hblk + (size_t)(col >> 2) * 131072 + (size_t)(col & 3) * 4;
    float s0 = 0.f, s1 = 0.f, q0 = 0.f, q1 = 0.f;
#pragma unroll
    for (int ob = 0; ob < 16; ++ob) {
        uint32_t d[8];
#pragma unroll
        for (int j = 0; j < 8; ++j) d[j] = p[(size_t)(ob * 8 + j) * 128];
#pragma unroll
        for (int j = 0; j < 8; ++j) {
            int r = r0 + ob * 8 + j;
            __builtin_nontemporal_store(d[j], (uint32_t*)(blkbase + (size_t)r * 16));
            float2 f = __half22float2(*(const __half2*)&d[j]);
            s0 += f.x; q0 = fmaf(f.x, f.x, q0);
            s1 += f.y; q1 = fmaf(f.y, f.y, q1);
        }
    }
    __shared__ float4 s_red[128];
    if (rp == 1) s_red[col] = make_float4(s0, s1, q0, q1);
    __syncthreads();
    if (rp == 0) {
        float4 r = s_red[col];
        atomicAdd(&gsum[2 * col],     s0 + r.x);
        atomicAdd(&gsum[2 * col + 1], s1 + r.y);
        atomicAdd(&gsq[2 * col],      q0 + r.z);
        atomicAdd(&gsq[2 * col + 1],  q1 + r.w);
    }
}

// ---------------------------------------------------------------------------
// stats over a BLOCKED table [32][8192][8]: one block per slab (exclusive
// ownership of its 8 batch cols -> non-atomic writes). Coalesced dwords.
// ---------------------------------------------------------------------------
__global__ __launch_bounds__(256) void stats_blk_kernel(const uint32_t* __restrict__ hblk,
                                                        float* __restrict__ gsum,
                                                        float* __restrict__ gsq) {
    int t = threadIdx.x;
    int s = blockIdx.x;                   // slab 0..31
    const uint32_t* p = hblk + (size_t)s * 32768;
    float s0 = 0.f, s1 = 0.f, q0 = 0.f, q1 = 0.f;
#pragma unroll 8
    for (int k = 0; k < 128; ++k) {
        uint32_t d = p[(size_t)k * 256 + t];
        float2 f = __half22float2(*(const __half2*)&d);
        s0 += f.x; q0 = fmaf(f.x, f.x, q0);
        s1 += f.y; q1 = fmaf(f.y, f.y, q1);
    }
    __shared__ float4 red[256];
    red[t] = make_float4(s0, s1, q0, q1);
    __syncthreads();
    if (t < 4) {
        float a0 = 0.f, a1 = 0.f, b0 = 0.f, b1 = 0.f;
        for (int m = 0; m < 64; ++m) {
            float4 r = red[t + 4 * m];
            a0 += r.x; a1 += r.y; b0 += r.z; b1 += r.w;
        }
        gsum[s * 8 + 2 * t]     = a0;
        gsum[s * 8 + 2 * t + 1] = a1;
        gsq[s * 8 + 2 * t]      = b0;
        gsq[s * 8 + 2 * t + 1]  = b1;
    }
}

// ---------------------------------------------------------------------------
// popcnt layer 1: ROUND-4 WINNER, unchanged. Global-gather path.
// ---------------------------------------------------------------------------
__global__ __launch_bounds__(256, 4) void popcnt_kernel(
    const __half* __restrict__ actT, const int* __restrict__ sel,
    const float* __restrict__ w, const float* __restrict__ bias,
    __half* __restrict__ outp) {
    const int o  = blockIdx.x;
    const int t  = threadIdx.x;
    const int cw = t & 31;
    const int rg = t >> 5;

    __shared__ uint32_t s_off[PSEL];
    __shared__ float    s_A[PSEL];
    __shared__ float s_acc[8][264];

    if (t < PSEL) {
        int idx  = __builtin_nontemporal_load(&sel[o * PSEL + t]);
        float ww = __builtin_nontemporal_load(&w[o * PSEL + t]);
        float sw = 1.0f / (1.0f + __expf(-ww));
        s_off[t] = (uint32_t)idx << 9;
        s_A[t]   = sw;
    }
    __syncthreads();

    const uint32_t lane_off = (uint32_t)(cw << 4);
    uint32_t voff[16];
#pragma unroll
    for (int j = 0; j < 16; ++j)
        voff[j] = s_off[j * 8 + rg] + lane_off;
    uint4 d[16];
#pragma unroll
    for (int j = 0; j < 16; ++j)
        asm volatile("global_load_dwordx4 %0, %1, %2 sc0"
                     : "=v"(d[j]) : "v"(voff[j]), "s"(actT) : "memory");
    asm volatile("s_waitcnt vmcnt(0)" ::: "memory");
    __builtin_amdgcn_sched_barrier(0);

    float acc[8] = {0.f, 0.f, 0.f, 0.f, 0.f, 0.f, 0.f, 0.f};
#pragma unroll
    for (int j = 0; j < 16; ++j) {
        float A = s_A[j * 8 + rg];
        const __half2* hp = (const __half2*)&d[j];
        float2 f0 = __half22float2(hp[0]);
        float2 f1 = __half22float2(hp[1]);
        float2 f2 = __half22float2(hp[2]);
        float2 f3 = __half22float2(hp[3]);
        acc[0] = fmaf(A, f0.x, acc[0]);
        acc[1] = fmaf(A, f0.y, acc[1]);
        acc[2] = fmaf(A, f1.x, acc[2]);
        acc[3] = fmaf(A, f1.y, acc[3]);
        acc[4] = fmaf(A, f2.x, acc[4]);
        acc[5] = fmaf(A, f2.y, acc[5]);
        acc[6] = fmaf(A, f3.x, acc[6]);
        acc[7] = fmaf(A, f3.y, acc[7]);
    }

    *(float4*)&s_acc[rg][8 * cw]     = make_float4(acc[0], acc[1], acc[2], acc[3]);
    *(float4*)&s_acc[rg][8 * cw + 4] = make_float4(acc[4], acc[5], acc[6], acc[7]);
    __syncthreads();

    float ab = 0.0f;
#pragma unroll
    for (int r = 0; r < 8; ++r) ab += s_acc[r][t];

    float z = ab - bias[o];
    float h = 1.0f / (1.0f + __expf(-z));
    __builtin_nontemporal_store(__half_as_ushort(__float2half(h)),
                                (unsigned short*)outp + (size_t)o * BATCH + t);
}

// ---------------------------------------------------------------------------
// popcnt layers 2/3, LDS-STAGED: block = (output-tile, batch-slab).
// Stage the slab's 128 KB activation table (8192 rows x 8 cols fp16) into
// dynamic LDS, then sweep nout outputs: 64 outputs/step, 8 lanes/output,
// 16 packed {off,A} entries per lane -> 16 ds_read_b128 random-row gathers.
// shfl-reduce over 8 lanes; leader applies folded layernorm + sigmoid and
// writes the 16 B blocked output row. Barrier-free main loop.
// ---------------------------------------------------------------------------
__global__ __launch_bounds__(512, 2) void popcnt_lds_kernel(
    const uint4* __restrict__ tblblk,   // [32][8192] uint4 (blocked fp16 table)
    const uint2* __restrict__ pack,     // [O][128] {ldsoff, A}
    const float2* __restrict__ meta,    // [O] {sA, sC - bias}
    const float* __restrict__ gsum, const float* __restrict__ gsq,
    float inv_n,
    __half* __restrict__ outblk,        // blocked output [32][O][8]
    int nout, int out_slab_halves) {
    extern __shared__ char smem[];      // 131072 B
    __shared__ float s_rs[8], s_rsm[8];
    const int t  = threadIdx.x;         // 0..511
    const int bt = blockIdx.x & 31;
    const int o0 = (blockIdx.x >> 5) * nout;

    if (t < 8) {
        float m = gsum[bt * 8 + t] * inv_n;
        float q = gsq[bt * 8 + t] * inv_n;
        float rs = rsqrtf(q - m * m + 1e-12f);
        s_rs[t] = rs;
        s_rsm[t] = rs * m;
    }
    // stage slab: 8192 uint4 / 512 threads = 16 coalesced iterations
    {
        const uint4* src = tblblk + (size_t)bt * 8192;
        uint4* dst = (uint4*)smem;
#pragma unroll
        for (int i = 0; i < 16; ++i) dst[i * 512 + t] = src[i * 512 + t];
    }
    __syncthreads();

    const int og = t >> 3;              // 0..63: output within step
    const int pc = t & 7;               // p-chunk
    const int nsteps = nout >> 6;
    for (int s = 0; s < nsteps; ++s) {
        const int o = o0 + s * 64 + og;
        const uint4* pk4 = (const uint4*)(pack + (size_t)o * PSEL + pc * 16);
        uint4 q[8];
#pragma unroll
        for (int m = 0; m < 8; ++m) q[m] = pk4[m];   // 8 coalesced 16B loads

        float acc[8] = {0.f, 0.f, 0.f, 0.f, 0.f, 0.f, 0.f, 0.f};
#pragma unroll
        for (int m = 0; m < 8; ++m) {
            uint4 da = *(const uint4*)(smem + q[m].x);
            float Aa = __uint_as_float(q[m].y);
            uint4 db = *(const uint4*)(smem + q[m].z);
            float Ab = __uint_as_float(q[m].w);
            const __half2* ha = (const __half2*)&da;
            const __half2* hb = (const __half2*)&db;
#pragma unroll
            for (int n = 0; n < 4; ++n) {
                float2 fa = __half22float2(ha[n]);
                float2 fb = __half22float2(hb[n]);
                acc[2 * n]     = fmaf(Aa, fa.x, acc[2 * n]);
                acc[2 * n + 1] = fmaf(Aa, fa.y, acc[2 * n + 1]);
                acc[2 * n]     = fmaf(Ab, fb.x, acc[2 * n]);
                acc[2 * n + 1] = fmaf(Ab, fb.y, acc[2 * n + 1]);
            }
        }
#pragma unroll
        for (int off = 4; off > 0; off >>= 1) {
#pragma unroll
            for (int j = 0; j < 8; ++j)
                acc[j] += __shfl_down(acc[j], off, 8);
        }
        if (pc == 0) {
            float2 mt = meta[o];
            float h[8];
#pragma unroll
            for (int j = 0; j < 8; ++j) {
                float z = s_rs[j] * acc[j] + mt.y - s_rsm[j] * mt.x;
                h[j] = 1.0f / (1.0f + __expf(-z));
            }
            u32x4 r;
            r.x = pack_half2(h[0], h[1]);
            r.y = pack_half2(h[2], h[3]);
            r.z = pack_half2(h[4], h[5]);
            r.w = pack_half2(h[6], h[7]);
            __builtin_nontemporal_store(
                r, (u32x4*)((unsigned short*)outblk + (size_t)bt * out_slab_halves +
                            (size_t)o * 8));
        }
    }
}

// ---------------------------------------------------------------------------
// final group-sum over BLOCKED h3 [32][4096][8]:
// out[b,g] = sum_{j<16} h3blk[b>>3][16g+j][b&7] - 8.
// ---------------------------------------------------------------------------
__global__ __launch_bounds__(256) void final_reduce(const unsigned short* __restrict__ h3blk,
                                                    float* __restrict__ out) {
    int gidx = blockIdx.x;
    int b    = threadIdx.x;
    const unsigned short* p =
        h3blk + (size_t)(b >> 3) * 32768 + (size_t)(16 * gidx) * 8 + (b & 7);
    float s = -8.0f;
#pragma unroll
    for (int j = 0; j < 16; ++j)
        s += __half2float(__ushort_as_half(__builtin_nontemporal_load(p + j * 8)));
    __builtin_nontemporal_store(s, &out[(size_t)b * 256 + gidx]);
}

// ---------------------------------------------------------------------------
extern "C" void kernel_launch(void* const* d_in, const int* in_sizes, int n_in,
                              void* d_out, int out_size, void* d_ws, size_t ws_size,
                              hipStream_t stream) {
    const float* x    = (const float*)d_in[0];
    const int*   sel1 = (const int*)d_in[1];
    const float* w1   = (const float*)d_in[2];
    const float* b1   = (const float*)d_in[3];
    const float* g1   = (const float*)d_in[4];
    const float* be1  = (const float*)d_in[5];
    const int*   sel2 = (const int*)d_in[6];
    const float* w2   = (const float*)d_in[7];
    const float* b2   = (const float*)d_in[8];
    const float* g2   = (const float*)d_in[9];
    const float* be2  = (const float*)d_in[10];
    const int*   sel3 = (const int*)d_in[11];
    const float* w3   = (const float*)d_in[12];
    const float* b3   = (const float*)d_in[13];
    float* out = (float*)d_out;

    // workspace layout (~29 MB)
    char* ws = (char*)d_ws;
    __half* xT    = (__half*)(ws);                 // 1,638,400
    __half* h1T   = (__half*)(ws + 1638400);       // 4,194,304 (row-major)
    __half* h1blk = (__half*)(ws + 5832704);       // 4,194,304 [32][8192][8]
    __half* h2blk = (__half*)(ws + 10027008);      // 4,194,304 [32][8192][8]
    __half* h3blk = (__half*)(ws + 14221312);      // 2,097,152 [32][4096][8]
    uint2*  pack2 = (uint2*)(ws + 16318464);       // 8,388,608
    uint2*  pack3 = (uint2*)(ws + 24707072);       // 4,194,304
    float2* meta2 = (float2*)(ws + 28901376);      // 65,536
    float2* meta3 = (float2*)(ws + 28966912);      // 32,768
    float*  stats = (float*)(ws + 28999680);       // 4,096
    float* gs1 = stats;
    float* gq1 = stats + 256;
    float* gs2 = stats + 512;
    float* gq2 = stats + 768;

    // allow 128 KB dynamic LDS for the staged kernel (idempotent)
    (void)hipFuncSetAttribute((const void*)popcnt_lds_kernel,
                              hipFuncAttributeMaxDynamicSharedMemorySize, 131072);

    // transpose + stats zero-init
    transpose_kernel<<<dim3(IN_DIM / 32, BATCH / 32), dim3(32, 8), 0, stream>>>(
        x, xT, stats);

    // precompute packed tables for layers 2 and 3 (independent of activations)
    pack_kernel<<<O1_DIM / 16, 256, 0, stream>>>(sel2, w2, g1, be1, b2, pack2, meta2);
    pack_kernel<<<O3_DIM / 16, 256, 0, stream>>>(sel3, w3, g2, be2, b3, pack3, meta3);

    // Layer 1: global-gather (round-4 winner), row-major output
    popcnt_kernel<<<O1_DIM, 256, 0, stream>>>(xT, sel1, w1, b1, h1T);

    // stats of h1 + blocked copy for staging
    stats_kernel<<<O1_DIM / 256, 256, 0, stream>>>(h1T, h1blk, gs1, gq1);

    // Layer 2: LDS-staged, layernorm(h1) folded; writes h2 blocked
    popcnt_lds_kernel<<<256, 512, 131072, stream>>>(
        (const uint4*)h1blk, pack2, meta2, gs1, gq1, 1.0f / (float)O1_DIM,
        h2blk, O1_DIM / 8, O1_DIM * 8);

    // stats of h2 (blocked, non-atomic)
    stats_blk_kernel<<<32, 256, 0, stream>>>((const uint32_t*)h2blk, gs2, gq2);

    // Layer 3: LDS-staged, layernorm(h2) folded; writes h3 blocked
    popcnt_lds_kernel<<<256, 512, 131072, stream>>>(
        (const uint4*)h2blk, pack3, meta3, gs2, gq2, 1.0f / (float)O1_DIM,
        h3blk, O3_DIM / 8, O3_DIM * 8);

    // final 16-wide group sum - 8
    final_reduce<<<256, 256, 0, stream>>>((const unsigned short*)h3blk, out);
}

// Round 10
// 182.584 us; speedup vs baseline: 1.2798x; 1.2798x over previous
//
#include <hip/hip_runtime.h>
#include <hip/hip_fp16.h>
#include <stdint.h>

// Problem constants (from reference setup_inputs)
#define BATCH 256
#define PSEL  128
#define IN_DIM 3200
#define O1_DIM 8192
#define O3_DIM 4096

// ---------------------------------------------------------------------------
// transpose x [256, 3200] fp32 -> xT [3200, 256] fp16
// Fused: zero the 4 x 256 float stats accumulators.
// ---------------------------------------------------------------------------
__global__ __launch_bounds__(256) void transpose_kernel(const float* __restrict__ x,
                                                        __half* __restrict__ xT,
                                                        float* __restrict__ stats) {
    int tx = threadIdx.x;       // 32
    int ty = threadIdx.y;       // 8
    int tid = ty * 32 + tx;
    int gid = blockIdx.y * gridDim.x + blockIdx.x;   // 0..799
    if (gid < 4) stats[gid * 256 + tid] = 0.0f;

    __shared__ float tile[32][33];
    int i0 = blockIdx.x * 32;   // input-dim tile (3200/32 = 100)
    int b0 = blockIdx.y * 32;   // batch tile    (256/32 = 8)
#pragma unroll
    for (int k = 0; k < 4; ++k)
        tile[ty + k * 8][tx] =
            __builtin_nontemporal_load(&x[(size_t)(b0 + ty + k * 8) * IN_DIM + i0 + tx]);
    __syncthreads();
#pragma unroll
    for (int k = 0; k < 4; ++k)
        xT[(size_t)(i0 + ty + k * 8) * BATCH + b0 + tx] =
            __float2half(tile[tx][ty + k * 8]);
}

// ---------------------------------------------------------------------------
// stats: per-batch-column sum / sum-of-squares of hT [8192, 256] fp16.
// 32 blocks x 256 rows (atomic tail: 32 same-address updates @~50ns =
// ~1.6us; streaming reads saturate). 8-deep load batches; LDS row-half
// combine; 4 atomics per column per block.
// ---------------------------------------------------------------------------
__global__ __launch_bounds__(256) void stats_kernel(const __half* __restrict__ hT,
                                                    float* __restrict__ gsum,
                                                    float* __restrict__ gsq) {
    int t   = threadIdx.x;
    int col = t & 127;          // dword column (batch 2col, 2col+1)
    int rp  = t >> 7;           // row half
    int r0  = blockIdx.x * 256 + rp * 128;
    const uint32_t* p = (const uint32_t*)hT + (size_t)r0 * 128 + col;
    float s0 = 0.f, s1 = 0.f, q0 = 0.f, q1 = 0.f;
#pragma unroll
    for (int ob = 0; ob < 16; ++ob) {
        uint32_t d[8];
#pragma unroll
        for (int j = 0; j < 8; ++j) d[j] = p[(size_t)(ob * 8 + j) * 128];
#pragma unroll
        for (int j = 0; j < 8; ++j) {
            float2 f = __half22float2(*(const __half2*)&d[j]);
            s0 += f.x; q0 = fmaf(f.x, f.x, q0);
            s1 += f.y; q1 = fmaf(f.y, f.y, q1);
        }
    }
    __shared__ float4 s_red[128];
    if (rp == 1) s_red[col] = make_float4(s0, s1, q0, q1);
    __syncthreads();
    if (rp == 0) {
        float4 r = s_red[col];
        atomicAdd(&gsum[2 * col],     s0 + r.x);
        atomicAdd(&gsum[2 * col + 1], s1 + r.y);
        atomicAdd(&gsq[2 * col],      q0 + r.z);
        atomicAdd(&gsq[2 * col + 1],  q1 + r.w);
    }
}

// ---------------------------------------------------------------------------
// popcnt layer: one block (256 threads) per output o. ROUND-4 WINNER BODY.
// Thread t: 16B chunk cw = t&31, row-group rg = t>>5. 16 sc0 (L1-bypass)
// dwordx4 gathers all in flight; LDS row-group exchange; layernorm folded;
// NT output store. Measured floor: ~3.3 cy per 64B line per CU, invariant
// across 8 structural variants (dword/dwordx4, 8/16-deep, +-L1, +-NT,
// +-pipeline, multi-output, LDS-staged).
// ---------------------------------------------------------------------------
template <bool NORM>
__global__ __launch_bounds__(256, 4) void popcnt_kernel(
    const __half* __restrict__ actT,  // [Nin, 256] fp16, rows = 512 B
    const int* __restrict__ sel,      // [Nout, 128]
    const float* __restrict__ w,      // [Nout, 128]
    const float* __restrict__ bias,   // [Nout]
    const float* __restrict__ g,      // [Nin]  (NORM only)
    const float* __restrict__ be,     // [Nin]  (NORM only)
    const float* __restrict__ gsum,   // [256]  (NORM only)
    const float* __restrict__ gsq,    // [256]  (NORM only)
    float inv_n,                      // 1/Nin  (NORM only)
    __half* __restrict__ outp)        // [Nout, 256] fp16
{
    const int o  = blockIdx.x;
    const int t  = threadIdx.x;       // 0..255
    const int cw = t & 31;            // 16-byte chunk within row
    const int rg = t >> 5;            // row group 0..7

    __shared__ uint32_t s_off[PSEL];          // byte offsets (idx*512)
    __shared__ float    s_A[PSEL];            // folded weights
    __shared__ float s_rA[PSEL], s_rC[PSEL];
    __shared__ float s_acc[8][264];           // padded: stride 264 -> 2-way max
    __shared__ float s_sums[2];

    if (t < PSEL) {
        int idx  = __builtin_nontemporal_load(&sel[o * PSEL + t]);
        float ww = __builtin_nontemporal_load(&w[o * PSEL + t]);
        float sw = 1.0f / (1.0f + __expf(-ww));   // resilu(w) == sigmoid(w)
        float a, c;
        if (NORM) { a = sw * g[idx]; c = sw * be[idx]; }
        else      { a = sw;          c = 0.0f; }
        s_off[t] = (uint32_t)idx << 9;            // idx * 512 B rows
        s_A[t]   = a;
        if (NORM) { s_rA[t] = a; s_rC[t] = c; }
    }
    __syncthreads();

    if (NORM && t < 64) {             // wave 0 reduces sumA, sumC over 128 entries
        float va = s_rA[t] + s_rA[t + 64];
        float vc = s_rC[t] + s_rC[t + 64];
#pragma unroll
        for (int off = 32; off > 0; off >>= 1) {
            va += __shfl_down(va, off, 64);
            vc += __shfl_down(vc, off, 64);
        }
        if (t == 0) { s_sums[0] = va; s_sums[1] = vc; }
    }

    // ---- gather: 16 L1-bypass (sc0) dwordx4 loads, all in flight ----
    const uint32_t lane_off = (uint32_t)(cw << 4);
    uint32_t voff[16];
#pragma unroll
    for (int j = 0; j < 16; ++j)
        voff[j] = s_off[j * 8 + rg] + lane_off;   // 2 distinct rows/wave: bcast
    uint4 d[16];
#pragma unroll
    for (int j = 0; j < 16; ++j)
        asm volatile("global_load_dwordx4 %0, %1, %2 sc0"
                     : "=v"(d[j])
                     : "v"(voff[j]), "s"(actT)
                     : "memory");
    asm volatile("s_waitcnt vmcnt(0)" ::: "memory");
    __builtin_amdgcn_sched_barrier(0);

    float acc[8] = {0.f, 0.f, 0.f, 0.f, 0.f, 0.f, 0.f, 0.f};
#pragma unroll
    for (int j = 0; j < 16; ++j) {
        float A = s_A[j * 8 + rg];
        const __half2* hp = (const __half2*)&d[j];
        float2 f0 = __half22float2(hp[0]);
        float2 f1 = __half22float2(hp[1]);
        float2 f2 = __half22float2(hp[2]);
        float2 f3 = __half22float2(hp[3]);
        acc[0] = fmaf(A, f0.x, acc[0]);
        acc[1] = fmaf(A, f0.y, acc[1]);
        acc[2] = fmaf(A, f1.x, acc[2]);
        acc[3] = fmaf(A, f1.y, acc[3]);
        acc[4] = fmaf(A, f2.x, acc[4]);
        acc[5] = fmaf(A, f2.y, acc[5]);
        acc[6] = fmaf(A, f3.x, acc[6]);
        acc[7] = fmaf(A, f3.y, acc[7]);
    }

    // ---- combine 8 row-groups: thread (cw,rg) owns batch 8cw..8cw+7 ----
    *(float4*)&s_acc[rg][8 * cw]     = make_float4(acc[0], acc[1], acc[2], acc[3]);
    *(float4*)&s_acc[rg][8 * cw + 4] = make_float4(acc[4], acc[5], acc[6], acc[7]);
    __syncthreads();   // also publishes s_sums

    float ab = 0.0f;
#pragma unroll
    for (int r = 0; r < 8; ++r) ab += s_acc[r][t];   // bank = (8r+t)%32: 2-way, free

    float bo = bias[o];
    float z;
    if (NORM) {
        float m  = gsum[t] * inv_n;
        float q  = gsq[t] * inv_n;
        float rs = rsqrtf(q - m * m + 1e-12f);
        z = rs * ab + s_sums[1] - rs * m * s_sums[0] - bo;
    } else {
        z = ab - bo;
    }
    float h = 1.0f / (1.0f + __expf(-z));
    __builtin_nontemporal_store(__half_as_ushort(__float2half(h)),
                                (unsigned short*)outp + (size_t)o * BATCH + t);
}

// ---------------------------------------------------------------------------
// final group-sum: out[b, g] = sum_{j<16} h3[16g+j, b] - 8.
// Coalesced reads, non-atomic scattered 4B writes (256 KB). Keeping this
// separate from layer 3 is worth ~35 us vs the atomic-fused variant
// (round-6 measurement: fused = 59 us, 32 MB write-through).
// ---------------------------------------------------------------------------
__global__ __launch_bounds__(256) void final_reduce(const __half* __restrict__ h3T,
                                                    float* __restrict__ out) {
    int gidx = blockIdx.x;     // group 0..255
    int b    = threadIdx.x;    // batch 0..255
    const unsigned short* p = (const unsigned short*)h3T + (size_t)gidx * 16 * BATCH + b;
    float s = -8.0f;
#pragma unroll
    for (int j = 0; j < 16; ++j)
        s += __half2float(__ushort_as_half(__builtin_nontemporal_load(p + j * BATCH)));
    __builtin_nontemporal_store(s, &out[(size_t)b * 256 + gidx]);
}

// ---------------------------------------------------------------------------
extern "C" void kernel_launch(void* const* d_in, const int* in_sizes, int n_in,
                              void* d_out, int out_size, void* d_ws, size_t ws_size,
                              hipStream_t stream) {
    const float* x    = (const float*)d_in[0];
    const int*   sel1 = (const int*)d_in[1];
    const float* w1   = (const float*)d_in[2];
    const float* b1   = (const float*)d_in[3];
    const float* g1   = (const float*)d_in[4];
    const float* be1  = (const float*)d_in[5];
    const int*   sel2 = (const int*)d_in[6];
    const float* w2   = (const float*)d_in[7];
    const float* b2   = (const float*)d_in[8];
    const float* g2   = (const float*)d_in[9];
    const float* be2  = (const float*)d_in[10];
    const int*   sel3 = (const int*)d_in[11];
    const float* w3   = (const float*)d_in[12];
    const float* b3   = (const float*)d_in[13];
    float* out = (float*)d_out;

    // workspace layout (fp16 activations); h3T reuses h1T (dead after layer 2)
    char* ws = (char*)d_ws;
    __half* xT  = (__half*)(ws);                          // 3200*256*2 = 1,638,400
    __half* h1T = (__half*)(ws + 1638400);                // 8192*256*2 = 4,194,304
    __half* h2T = (__half*)(ws + 1638400 + 4194304);      // 4,194,304
    __half* h3T = h1T;                                    // 4096*256*2 = 2,097,152
    float* stats = (float*)(ws + 1638400 + 2 * 4194304);  // 4 * 256 floats
    float* gs1 = stats;
    float* gq1 = stats + 256;
    float* gs2 = stats + 512;
    float* gq2 = stats + 768;

    // transpose + stats zero-init fused
    transpose_kernel<<<dim3(IN_DIM / 32, BATCH / 32), dim3(32, 8), 0, stream>>>(
        x, xT, stats);

    // Layer 1: x -> h1 (no input norm)
    popcnt_kernel<false><<<O1_DIM, 256, 0, stream>>>(
        xT, sel1, w1, b1, nullptr, nullptr, nullptr, nullptr, 0.0f, h1T);

    // stats of h1 for layernorm 1
    stats_kernel<<<O1_DIM / 256, 256, 0, stream>>>(h1T, gs1, gq1);

    // Layer 2: layernorm(h1) folded in
    popcnt_kernel<true><<<O1_DIM, 256, 0, stream>>>(
        h1T, sel2, w2, b2, g1, be1, gs1, gq1, 1.0f / (float)O1_DIM, h2T);

    // stats of h2 for layernorm 2
    stats_kernel<<<O1_DIM / 256, 256, 0, stream>>>(h2T, gs2, gq2);

    // Layer 3: layernorm(h2) folded in, writes h3 rows (no atomics)
    popcnt_kernel<true><<<O3_DIM, 256, 0, stream>>>(
        h2T, sel3, w3, b3, g2, be2, gs2, gq2, 1.0f / (float)O1_DIM, h3T);

    // final 16-wide group sum - 8
    final_reduce<<<256, 256, 0, stream>>>(h3T, out);
}